// Round 1
// baseline (170.633 us; speedup 1.0000x reference)
//
#include <hip/hip_runtime.h>

// FusionLoss: scalar loss over (B=128, J=16, H=128, W=128) inputs.
// Inputs (setup_inputs order):
//   d_in[0] output  float32  [128,16,128,128]
//   d_in[1] mask    int32    [128,16]
//   d_in[2] ind     int32    [128,16]
//   d_in[3] target  float32  [128,16,1]   (also 'visible' in var loss)
//   d_in[4] gt_2d   float32  [128,32]
// Output: scalar float32.

#define NB 128
#define NJ 16
#define NH 128
#define NW 128
#define NE 12
#define NG 4

__global__ __launch_bounds__(128) void fusion_loss_kernel(
    const float* __restrict__ output,
    const int*   __restrict__ mask,
    const int*   __restrict__ ind,
    const float* __restrict__ target,
    const float* __restrict__ gt2d,
    float*       __restrict__ out)
{
    const int b = threadIdx.x;            // one thread per batch, 0..127

    // edge tables (compile-time constants; live in SGPRs/inline)
    const int   id1[NE] = {0,1,3,4,10,11,13,14,2,3,12,13};
    const int   id2[NE] = {1,2,4,5,11,12,14,15,6,6,8,8};
    const int   gid[NE] = {0,0,0,0,1,1,1,1,2,2,3,3};
    const float wsk[NE] = {1.0085885098415446f, 1.0f, 1.0f, 1.0085885098415446f,
                           1.1375361376887123f, 1.0f, 1.0f, 1.1375361376887123f,
                           1.0f, 1.0f, 1.0f, 1.0f};

    const int*   indb = ind    + b * NJ;
    const float* tb   = target + b * NJ;
    const int*   mb   = mask   + b * NJ;
    const float* gb   = gt2d   + b * 2 * NJ;
    const float* ob   = output + (size_t)b * NJ * NH * NW;

    // ---- gather pred + load per-batch vectors (all loads issued up front) ----
    float pred[NJ], vis[NJ];
    int   msk[NJ];
    float xy0[NJ], xy1[NJ];
#pragma unroll
    for (int j = 0; j < NJ; ++j) {
        int t  = indb[j];
        int jj = t & (NJ - 1);       // feat layout: h*(W*J) + w*J + j
        int hw = t >> 4;             // = h*W + w
        pred[j] = ob[jj * (NH * NW) + hw];
        vis[j]  = tb[j];
        msk[j]  = mb[j];
        xy0[j]  = gb[2 * j];
        xy1[j]  = gb[2 * j + 1];
    }

    // ---- reg loss partials (mask is zeros in practice, computed generically) ----
    float sl1  = 0.0f;   // smooth-L1 partial sum
    float numm = 0.0f;   // mask count partial
    int   masksum = 0;
#pragma unroll
    for (int j = 0; j < NJ; ++j) {
        float m  = (float)msk[j];
        float d  = pred[j] * m - vis[j] * m;
        float ad = fabsf(d);
        sl1  += (ad < 1.0f) ? 0.5f * d * d : ad - 0.5f;
        numm += m;
        masksum += msk[j];
    }

    // ---- var loss: 12 edges, 4 groups, all in registers ----
    float gnum[NG] = {0.f, 0.f, 0.f, 0.f};
    float gsum[NG] = {0.f, 0.f, 0.f, 0.f};
    float lv[NE];
    bool  vv[NE];
#pragma unroll
    for (int e = 0; e < NE; ++e) {
        const int a = id1[e], c = id2[e];
        const bool v = (vis[a] > 0.5f) && (vis[c] > 0.5f);
        float dx  = xy0[a] - xy0[c];
        float dy  = xy1[a] - xy1[c];
        float d2d = dx * dx + dy * dy;
        float dzv = pred[a] - pred[c];
        float s   = v ? (d2d + dzv * dzv) : 1.0f;
        float l   = v ? sqrtf(s) * wsk[e] : 0.0f;
        lv[e] = l;
        vv[e] = v;
        gnum[gid[e]] += v ? 1.0f : 0.0f;
        gsum[gid[e]] += l;
    }

    float E[NG];
#pragma unroll
    for (int g = 0; g < NG; ++g)
        E[g] = (gnum[g] >= 0.5f) ? gsum[g] / fmaxf(gnum[g], 1.0f) : 0.0f;

    float tot = 0.0f;
#pragma unroll
    for (int e = 0; e < NE; ++e) {
        if (vv[e]) {
            float ne = fmaxf(gnum[gid[e]], 1.0f);
            float dd = lv[e] - E[gid[e]];
            tot += dd * dd / (2.0f * ne);
        }
    }
    // active[b] = (sum_j mask[b,j] == 0)
    if (masksum != 0) tot = 0.0f;

    // ---- reduce sl1, numm, tot across 128 threads (2 waves) ----
#pragma unroll
    for (int off = 32; off > 0; off >>= 1) {
        sl1  += __shfl_down(sl1,  off, 64);
        numm += __shfl_down(numm, off, 64);
        tot  += __shfl_down(tot,  off, 64);
    }
    __shared__ float s_sl1[2], s_num[2], s_tot[2];
    const int wave = threadIdx.x >> 6;
    const int lane = threadIdx.x & 63;
    if (lane == 0) { s_sl1[wave] = sl1; s_num[wave] = numm; s_tot[wave] = tot; }
    __syncthreads();
    if (threadIdx.x == 0) {
        float S = s_sl1[0] + s_sl1[1];
        float N = s_num[0] + s_num[1];
        float T = s_tot[0] + s_tot[1];
        // loss = REG_WEIGHT * sl1/(num+1e-4) + VAR_WEIGHT * total / B
        out[0] = S / (N + 0.0001f) + 0.01f * T / 128.0f;
    }
}

extern "C" void kernel_launch(void* const* d_in, const int* in_sizes, int n_in,
                              void* d_out, int out_size, void* d_ws, size_t ws_size,
                              hipStream_t stream) {
    const float* output = (const float*)d_in[0];
    const int*   mask   = (const int*)  d_in[1];
    const int*   ind    = (const int*)  d_in[2];
    const float* target = (const float*)d_in[3];
    const float* gt2d   = (const float*)d_in[4];
    float*       out    = (float*)d_out;

    fusion_loss_kernel<<<1, 128, 0, stream>>>(output, mask, ind, target, gt2d, out);
}